// Round 1
// baseline (175.508 us; speedup 1.0000x reference)
//
#include <hip/hip_runtime.h>
#include <math.h>

typedef unsigned short u16;
typedef unsigned int u32;
typedef __attribute__((ext_vector_type(2))) __fp16 half2;
typedef __attribute__((ext_vector_type(8))) __fp16 half8;
typedef __attribute__((ext_vector_type(16))) float floatx16;

constexpr int CB = 8;      // batch
constexpr int CS = 2048;   // seq
constexpr int CE = 256;    // emb
constexpr int CH = 8;      // heads
constexpr int CD = 32;     // head dim
constexpr float CLN_EPS = 1e-5f;
// scores get exp2 via poly; fold scale * log2(e) into Q at projection time
constexpr float QSC = 0.0625f * 1.44269504088896341f;

constexpr int XP = 268;   // lds pitch (shorts) for x tile (max 2-way banks)
constexpr int RST = 4104; // revg8 per-(h,p) stride in shorts

__device__ inline u32 fbits(float f) { union { float f; u32 u; } c; c.f = f; return c.u; }
// pack two f32 -> two f16 in one dword (v_cvt_pkrtz_f16_f32, 1 inst; low half = a)
__device__ inline u32 pkrtz(float a, float b) {
  half2 h = __builtin_amdgcn_cvt_pkrtz(a, b);
  union { half2 h; u32 u; } c; c.h = h; return c.u;
}
__device__ inline u16 h1(float a) {
  union { __fp16 h; u16 u; } c; c.h = (__fp16)a; return c.u;
}
__device__ inline half8 ldh8(const u16* p) {
  union { uint4 q; half8 v; } c; c.q = *(const uint4*)p; return c.v;
}

// v_permlane32_swap_b32: a' = {a.lo32, b.lo32}, b' = {a.hi32, b.hi32}
#if __has_builtin(__builtin_amdgcn_permlane32_swap)
__device__ inline void swap32(u32& a, u32& b) {
  typedef __attribute__((ext_vector_type(2))) unsigned int uint2v;
  uint2v r = __builtin_amdgcn_permlane32_swap(a, b, false, false);
  a = r[0]; b = r[1];
}
#else
__device__ inline void swap32(u32& a, u32& b) {
  int hi = (threadIdx.x >> 5) & 1;
  u32 sa = (u32)__shfl_xor((int)a, 32);
  u32 sb = (u32)__shfl_xor((int)b, 32);
  u32 na = hi ? sb : a;
  u32 nb = hi ? b : sa;
  a = na; b = nb;
}
#endif

// ------------- prep (merged): W f32->f16  +  reversed bias 8-shift copies (f16) -------
__global__ __launch_bounds__(256) void prep_kernel(
    const float* __restrict__ Wq, const float* __restrict__ Wk,
    const float* __restrict__ Wv, const float* __restrict__ table,
    u16* __restrict__ Wb, u16* __restrict__ revg) {
  int gid = blockIdx.x * 256 + threadIdx.x;
  if (gid < 49152) {                           // W convert: 3 * 16384 float4s
    int which = gid >> 14;
    int off = (gid & 16383) * 4;
    const float* W = (which == 0) ? Wq : (which == 1) ? Wk : Wv;
    float4 f = *(const float4*)&W[off];
    uint2 o; o.x = pkrtz(f.x, f.y); o.y = pkrtz(f.z, f.w);
    *(uint2*)&Wb[(size_t)which * CE * CE + off] = o;
  } else {
    int gid2 = gid - 49152;                    // 64*513 = 32832 uint4 groups
    if (gid2 >= 64 * 513) return;
    int g = gid2 / 513;                        // h*8 + p
    int j0 = (gid2 - g * 513) * 8;
    int h = g >> 3, p = g & 7;
    u16 vals[8];
#pragma unroll
    for (int t = 0; t < 8; ++t) {
      int src = 4094 - (j0 + t + p);
      vals[t] = (src >= 0) ? h1(table[(size_t)src * CH + h]) : (u16)0;
    }
    *(uint4*)&revg[(size_t)g * RST + j0] = *(uint4*)vals;
  }
}

// ---------------- QKV: y = x @ W.T via f16 MFMA (A = W, B = x^T) ----------------
// grid (256, 3): block = 64 s-rows x ALL 256 features of one matrix (q/k/v).
// x tile staged to LDS ONCE per block; W f16 streamed from L2 in k-loop.
// C layout: lane = s, regs = features. q,k f16 [bh][s][d] (q pre-scaled);
// v TRANSPOSED f16 [bh][d][s].
__global__ __launch_bounds__(256, 4) void qkv_mfma_kernel(
    const float* __restrict__ x, const u16* __restrict__ Wb,
    u16* __restrict__ qb, u16* __restrict__ kb, u16* __restrict__ vb) {
  __shared__ __attribute__((aligned(16))) u16 Xs[64 * XP];
  const int m0 = blockIdx.x * 64;
  const int which = blockIdx.y;                // 0=q 1=k 2=v
  const int tid = threadIdx.x;
  const int lane = tid & 63, wv = tid >> 6;
  const int lm = lane & 31, lg = lane >> 5;

  // stage x tile 64x256 f32 -> f16 (once per block)
#pragma unroll
  for (int it = 0; it < 16; ++it) {
    int c = tid + 256 * it;                    // 0..4095 float4-units
    int row = c >> 6, f4 = c & 63;
    float4 f = *(const float4*)&x[(size_t)(m0 + row) * CE + f4 * 4];
    uint2 o; o.x = pkrtz(f.x, f.y); o.y = pkrtz(f.z, f.w);
    *(uint2*)&Xs[row * XP + f4 * 4] = o;
  }
  __syncthreads();

  const u16* Wsrc = Wb + (size_t)which * CE * CE;

#pragma unroll
  for (int r = 0; r < 2; ++r) {
    const int F = wv * 32 + r * 128;           // this wave's feature tile (= head F>>5)
    floatx16 acc0, acc1;                       // m-subtiles: s rows 0-31, 32-63
#pragma unroll
    for (int i = 0; i < 16; ++i) { acc0[i] = 0.f; acc1[i] = 0.f; }
#pragma unroll
    for (int kt = 0; kt < 16; ++kt) {
      half8 wfr = ldh8(&Wsrc[(size_t)(F + lm) * CE + kt * 16 + lg * 8]);  // L2-hot
      half8 b0 = ldh8(&Xs[lm * XP + kt * 16 + lg * 8]);
      half8 b1 = ldh8(&Xs[(32 + lm) * XP + kt * 16 + lg * 8]);
      acc0 = __builtin_amdgcn_mfma_f32_32x32x16_f16(wfr, b0, acc0, 0, 0, 0);
      acc1 = __builtin_amdgcn_mfma_f32_32x32x16_f16(wfr, b1, acc1, 0, 0, 0);
    }
    const int hh = F >> 5;
#pragma unroll
    for (int ms = 0; ms < 2; ++ms) {
      floatx16& acc = ms ? acc1 : acc0;
      const int sg = m0 + ms * 32 + lm;
      const int bI = sg >> 11, sI = sg & (CS - 1);
      if (which < 2) {
        u16* dst = which ? kb : qb;
        float scl = which ? 1.0f : QSC;
        u32 D[8];
#pragma unroll
        for (int g = 0; g < 8; ++g)
          D[g] = pkrtz(acc[2 * g] * scl, acc[2 * g + 1] * scl);
        swap32(D[0], D[2]); swap32(D[1], D[3]);
        swap32(D[4], D[6]); swap32(D[5], D[7]);
        size_t base = (((size_t)bI * CH + hh) * CS + sI) * CD;
        uint4 U0; U0.x = D[0]; U0.y = D[1]; U0.z = D[2]; U0.w = D[3];
        uint4 U1; U1.x = D[4]; U1.y = D[5]; U1.z = D[6]; U1.w = D[7];
        *(uint4*)&dst[base + 8 * lg] = U0;
        *(uint4*)&dst[base + 16 + 8 * lg] = U1;
      } else {
        // v transposed [bh][d][s]: lane lm = s consecutive -> coalesced b16 stores
#pragma unroll
        for (int rg = 0; rg < 16; ++rg) {
          int d = (rg & 3) + 8 * (rg >> 2) + 4 * lg;
          vb[(((size_t)bI * CH + hh) * CD + d) * CS + sI] = h1(acc[rg]);
        }
      }
    }
  }
}

// ---------------- attention v2: barrier-free / LDS-free, 64 q per wave ----------------
// Old structure: LDS-staged K/V + one __syncthreads per 64-k tile. Counters showed
// MfmaUtil 33 / VALUBusy 42 / Occ 31 -> ~55% of every tile slot all-pipes-idle:
// the barrier convoys 4 waves into the same phase. But the LDS tiles were stored in
// the exact linear layout of the global q/k/v buffers (pure pass-through), so MFMA
// fragments can be gathered straight from global (L1/L2-hot). Waves become fully
// independent: no barrier, no LDS, stalls interleave instead of synchronizing.
// Each wave now owns 64 q rows (two 32-row subtiles) so the K/V fragment fetch is
// amortized 2x -> vector-memory traffic ~1.05 GB, under the ~35 TB/s L1/L2 ceiling.
// Grid is linear with bh = id & 63: co-resident blocks on a CU (ids differ by 256)
// share bh -> K/V tiles L1-shared; all blocks of an XCD (id mod 8) share h -> one
// 65 KB bias stream + 8 bh x 256 KB K/V per XCD L2 (2 MB < 4 MB).
__global__ __launch_bounds__(256, 2) void attn_mfma_kernel(
    const u16* __restrict__ qm, const u16* __restrict__ km,
    const u16* __restrict__ vm, const u16* __restrict__ revg,
    float* __restrict__ out) {
  const int id = blockIdx.x;
  const int bh = id & 63;                 // L1/L2 co-residency swizzle
  const int q0 = (id >> 6) * 256;         // 8 q-blocks of 256 rows
  const int b = bh >> 3, h = bh & 7;
  const int tid = threadIdx.x;
  const int lane = tid & 63, wv = tid >> 6;
  const int lm = lane & 31, lg = lane >> 5;
  const u16* qbp = qm + (size_t)bh * CS * CD;
  const u16* kbp = km + (size_t)bh * CS * CD;
  const u16* vbp = vm + (size_t)bh * CD * CS;   // transposed [d][s]

  // two q-subtiles per wave: rows qrA and qrA+32 (within the block's 256 rows)
  const int qrA = wv * 64 + lm, qrB = qrA + 32;
  const u16* qpA = qbp + (size_t)(q0 + qrA) * CD;
  const u16* qpB = qbp + (size_t)(q0 + qrB) * CD;
  half8 qa0A = ldh8(qpA + lg * 8), qa1A = ldh8(qpA + 16 + lg * 8);
  half8 qa0B = ldh8(qpB + lg * 8), qa1B = ldh8(qpB + 16 + lg * 8);

  // per-lane bias stream pointers (X % 8 is loop-invariant)
  const int XbA = 2047 - q0 - qrA + lg * 8;
  const int ppA = XbA & 7;
  const u16* bpA = revg + (size_t)(h * 8 + ppA) * RST + (XbA - ppA);
  const int XbB = XbA - 32;
  const int ppB = XbB & 7;
  const u16* bpB = revg + (size_t)(h * 8 + ppB) * RST + (XbB - ppB);

  // exp2 poly coefficients (degree 3, |x|<=0.36, err ~5e-5)
  const half2 PC3 = {(__fp16)0.0558022f, (__fp16)0.0558022f};
  const half2 PC2 = {(__fp16)0.2401997f, (__fp16)0.2401997f};
  const half2 PC1 = {(__fp16)0.6931472f, (__fp16)0.6931472f};
  const half2 PC0 = {(__fp16)1.0f, (__fp16)1.0f};

  // named zero vector: C-operand for the first mfma of each score chain
  // (replaces 32 v_mov zero-inits per tile with persistent zero regs)
  floatx16 zf;
#pragma unroll
  for (int i = 0; i < 16; ++i) zf[i] = 0.f;
  floatx16 aeA = zf, abA = zf, aeB = zf, abB = zf;
  float lA = 0.f, lB = 0.f;

#define SUBTILE(QA0, QA1, BU0, BU1, BU2, BU3, AE, AB, LL)                        \
  {                                                                              \
    __builtin_amdgcn_s_setprio(1);                                               \
    floatx16 sc0 = __builtin_amdgcn_mfma_f32_32x32x16_f16(a00, QA0, zf, 0, 0, 0);\
    sc0 = __builtin_amdgcn_mfma_f32_32x32x16_f16(a01, QA1, sc0, 0, 0, 0);        \
    floatx16 sc1 = __builtin_amdgcn_mfma_f32_32x32x16_f16(a10, QA0, zf, 0, 0, 0);\
    sc1 = __builtin_amdgcn_mfma_f32_32x32x16_f16(a11, QA1, sc1, 0, 0, 0);        \
    __builtin_amdgcn_s_setprio(0);                                               \
    half2 lacc = {(__fp16)0.0f, (__fp16)0.0f};                                   \
    _Pragma("unroll")                                                            \
    for (int ct = 0; ct < 2; ++ct) {                                             \
      floatx16& sc = ct ? sc1 : sc0;                                             \
      u32 P[8];                                                                  \
      _Pragma("unroll")                                                          \
      for (int g = 0; g < 8; ++g) {                                              \
        half2 xv = __builtin_amdgcn_cvt_pkrtz(sc[2 * g], sc[2 * g + 1]);         \
        half2 r = __builtin_elementwise_fma(PC3, xv, PC2);                       \
        r = __builtin_elementwise_fma(r, xv, PC1);                               \
        r = __builtin_elementwise_fma(r, xv, PC0);                               \
        lacc += r;                                                               \
        union { half2 hh; u32 u; } cc; cc.hh = r;                                \
        P[g] = cc.u;                                                             \
      }                                                                          \
      swap32(P[0], P[2]); swap32(P[1], P[3]);                                    \
      swap32(P[4], P[6]); swap32(P[5], P[7]);                                    \
      union { u32 u[4]; half8 v; } B0, B1;                                       \
      B0.u[0] = P[0]; B0.u[1] = P[1]; B0.u[2] = P[2]; B0.u[3] = P[3];            \
      B1.u[0] = P[4]; B1.u[1] = P[5]; B1.u[2] = P[6]; B1.u[3] = P[7];            \
      half8 va0 = ct ? va10 : va00;                                              \
      half8 va1 = ct ? va11 : va01;                                              \
      union { uint4 q; half8 v; } Bb0, Bb1;                                      \
      Bb0.q = ct ? BU2 : BU0;                                                    \
      Bb1.q = ct ? BU3 : BU1;                                                    \
      __builtin_amdgcn_s_setprio(1);                                             \
      AE = __builtin_amdgcn_mfma_f32_32x32x16_f16(va0, B0.v, AE, 0, 0, 0);       \
      AE = __builtin_amdgcn_mfma_f32_32x32x16_f16(va1, B1.v, AE, 0, 0, 0);       \
      AB = __builtin_amdgcn_mfma_f32_32x32x16_f16(va0, Bb0.v, AB, 0, 0, 0);      \
      AB = __builtin_amdgcn_mfma_f32_32x32x16_f16(va1, Bb1.v, AB, 0, 0, 0);      \
      __builtin_amdgcn_s_setprio(0);                                             \
    }                                                                            \
    LL += (float)lacc[0] + (float)lacc[1];                                       \
  }

  for (int k0 = 0; k0 < CS; k0 += 64) {
    // K A-fragments straight from global (same linear layout LDS used to mirror);
    // issue all 16 tile loads up-front: K first (consumed first), then V, then bias
    // (consumed last) -> natural counted-vmcnt pipeline, no barrier anywhere.
    const u16* kk = kbp + (size_t)k0 * CD;
    half8 a00 = ldh8(kk + lm * CD + lg * 8);
    half8 a01 = ldh8(kk + lm * CD + 16 + lg * 8);
    half8 a10 = ldh8(kk + (32 + lm) * CD + lg * 8);
    half8 a11 = ldh8(kk + (32 + lm) * CD + 16 + lg * 8);
    const u16* vk = vbp + (size_t)lm * CS + k0;   // lane lm = d row
    half8 va00 = ldh8(vk + lg * 8);
    half8 va01 = ldh8(vk + 16 + lg * 8);
    half8 va10 = ldh8(vk + 32 + lg * 8);
    half8 va11 = ldh8(vk + 48 + lg * 8);
    uint4 buA0 = *(const uint4*)&bpA[k0];
    uint4 buA1 = *(const uint4*)&bpA[k0 + 16];
    uint4 buA2 = *(const uint4*)&bpA[k0 + 32];
    uint4 buA3 = *(const uint4*)&bpA[k0 + 48];
    uint4 buB0 = *(const uint4*)&bpB[k0];
    uint4 buB1 = *(const uint4*)&bpB[k0 + 16];
    uint4 buB2 = *(const uint4*)&bpB[k0 + 32];
    uint4 buB3 = *(const uint4*)&bpB[k0 + 48];

    SUBTILE(qa0A, qa1A, buA0, buA1, buA2, buA3, aeA, abA, lA)
    SUBTILE(qa0B, qa1B, buB0, buB1, buB2, buB3, aeB, abB, lB)
  }
#undef SUBTILE

  // l: the two lg-halves hold complementary halves of row q's sum
  lA += __shfl_xor(lA, 32);
  lB += __shfl_xor(lB, 32);
  float rlA = __builtin_amdgcn_rcpf(lA);
  float rlB = __builtin_amdgcn_rcpf(lB);
  // O^T C-layout: lane = q, regs = d in groups of 4 -> float4 stores
  size_t obA = ((size_t)b * CS + q0 + qrA) * CE + h * CD;
  size_t obB = ((size_t)b * CS + q0 + qrB) * CE + h * CD;
#pragma unroll
  for (int g = 0; g < 4; ++g) {
    float4 r4;
    r4.x = aeA[4 * g + 0] * rlA + abA[4 * g + 0];
    r4.y = aeA[4 * g + 1] * rlA + abA[4 * g + 1];
    r4.z = aeA[4 * g + 2] * rlA + abA[4 * g + 2];
    r4.w = aeA[4 * g + 3] * rlA + abA[4 * g + 3];
    *(float4*)&out[obA + 8 * g + 4 * lg] = r4;
    float4 s4;
    s4.x = aeB[4 * g + 0] * rlB + abB[4 * g + 0];
    s4.y = aeB[4 * g + 1] * rlB + abB[4 * g + 1];
    s4.z = aeB[4 * g + 2] * rlB + abB[4 * g + 2];
    s4.w = aeB[4 * g + 3] * rlB + abB[4 * g + 3];
    *(float4*)&out[obB + 8 * g + 4 * lg] = s4;
  }
}

// ---------------- LayerNorm over E: one wave per row, float4 per lane ----------------
__global__ __launch_bounds__(256) void ln_kernel(float* __restrict__ io,
                                                 const float* __restrict__ gamma,
                                                 const float* __restrict__ beta) {
  int tid = threadIdx.x;
  size_t row = (size_t)blockIdx.x * 4 + (tid >> 6);
  int c = (tid & 63) * 4;
  float4 v = *(const float4*)&io[row * CE + c];
  float s1 = v.x + v.y + v.z + v.w;
  float s2 = v.x * v.x + v.y * v.y + v.z * v.z + v.w * v.w;
#pragma unroll
  for (int off = 1; off < 64; off <<= 1) {
    s1 += __shfl_xor(s1, off);
    s2 += __shfl_xor(s2, off);
  }
  float mu = s1 * (1.0f / CE);
  float var = s2 * (1.0f / CE) - mu * mu;
  float rs = rsqrtf(var + CLN_EPS);
  float4 g = *(const float4*)&gamma[c];
  float4 be = *(const float4*)&beta[c];
  float4 o;
  o.x = (v.x - mu) * rs * g.x + be.x;
  o.y = (v.y - mu) * rs * g.y + be.y;
  o.z = (v.z - mu) * rs * g.z + be.z;
  o.w = (v.w - mu) * rs * g.w + be.w;
  *(float4*)&io[row * CE + c] = o;
}

extern "C" void kernel_launch(void* const* d_in, const int* in_sizes, int n_in,
                              void* d_out, int out_size, void* d_ws, size_t ws_size,
                              hipStream_t stream) {
  (void)in_sizes; (void)n_in; (void)out_size; (void)ws_size;
  const float* x          = (const float*)d_in[0];
  const float* Wq         = (const float*)d_in[1];
  const float* Wk         = (const float*)d_in[2];
  const float* Wv         = (const float*)d_in[3];
  const float* bias_table = (const float*)d_in[4];
  const float* gamma      = (const float*)d_in[5];
  const float* beta       = (const float*)d_in[6];
  float* out = (float*)d_out;

  // ws layout (u16): Wb[3*256*256] | qb | kb | vb(transposed) | revg8[64*4104]  ~26.2 MB
  u16* ws = (u16*)d_ws;
  u16* Wb = ws;
  u16* qb = Wb + 3 * CE * CE;
  u16* kb = qb + (size_t)CB * CH * CS * CD;
  u16* vb = kb + (size_t)CB * CH * CS * CD;
  u16* revg = vb + (size_t)CB * CH * CS * CD;

  prep_kernel<<<dim3(321), dim3(256), 0, stream>>>(Wq, Wk, Wv, bias_table, Wb, revg);
  qkv_mfma_kernel<<<dim3(256, 3), dim3(256), 0, stream>>>(x, Wb, qb, kb, vb);
  attn_mfma_kernel<<<dim3(512), dim3(256), 0, stream>>>(qb, kb, vb, revg, out);
  ln_kernel<<<dim3(CB * CS / 4), dim3(256), 0, stream>>>(out, gamma, beta);
}